// Round 8
// baseline (839.478 us; speedup 1.0000x reference)
//
#include <hip/hip_runtime.h>
#include <hip/hip_bf16.h>

// SRPBlock forward — fp16 end-to-end MFMA implicit-GEMM convs + LDS-tiled local attention.
// x=concat(old,new) [4,64,256,256] fp32 NCHW inputs; all activations flow as fp16
// [b][pix][ch] (channel-contiguous); fp32 accumulate everywhere; final out fp32 NCHW.
//
// This revision (deepen R7's pipelining; R7 = 833 us):
//  * conv_mfma CIN=64: full 64-ch input halo staged ONCE (40.5 KB, [pix][64] swizzled);
//    tap-group loop ({0,1},{2,3},{4,5},{6,7},{8}) with 2x16KB weight RING buffer —
//    next group's weights stage while current group computes; the group barrier
//    drains them for free. NO serial drain after the prologue. LDS 72.5 KB, 2 blk/CU.
//  * conv_mfma CIN=96 (1 kernel): R7 path unchanged (input dbuf + per-chunk weights).
//  * local_sim: round-2 version verbatim (~70 us).

#define HH 256
#define WW 256
#define PLANE 65536

typedef _Float16 f16x8 __attribute__((ext_vector_type(8)));
typedef float    f32x4 __attribute__((ext_vector_type(4)));
typedef _Float16 h2    __attribute__((ext_vector_type(2)));

__device__ __forceinline__ unsigned short f2h(float f) {
    _Float16 h = (_Float16)f;                  // v_cvt_f16_f32 (RNE)
    return __builtin_bit_cast(unsigned short, h);
}
__device__ __forceinline__ float h2f(unsigned short u) {
    return (float)__builtin_bit_cast(_Float16, u);
}
__device__ __forceinline__ unsigned pack2h(float a, float b) {
    return (unsigned)f2h(a) | ((unsigned)f2h(b) << 16);
}
__device__ __forceinline__ float dot2h(unsigned a, unsigned b, float c) {
#if __has_builtin(__builtin_amdgcn_fdot2)
    return __builtin_amdgcn_fdot2(__builtin_bit_cast(h2, a),
                                  __builtin_bit_cast(h2, b), c, false);
#else
    h2 av = __builtin_bit_cast(h2, a), bv = __builtin_bit_cast(h2, b);
    return fmaf((float)av.x, (float)bv.x, fmaf((float)av.y, (float)bv.y, c));
#endif
}

// async 16B global -> LDS. LDS dest is wave-uniform base + lane*16 (linear);
// per-lane swizzling must be applied to the GLOBAL source address.
__device__ __forceinline__ void gl16(const unsigned short* g, unsigned short* l) {
    __builtin_amdgcn_global_load_lds(
        (const __attribute__((address_space(1))) unsigned int*)(g),
        (__attribute__((address_space(3))) unsigned int*)(l),
        16, 0, 0);
}

// ---------------- conv3x3 (pad=1, Cout=64) via MFMA 16x16x32 f16 ----------------
// block = 256 thr = 4 waves; tile = 16x16 pixels x 64 outch; grid (16,16,4).
template <int CIN, bool BIAS, bool LEAKY, bool ADDF, bool ADDX, bool MULX, bool OUTF, bool OUTB>
__global__ __launch_bounds__(256, 2) void conv_mfma(
    const unsigned short* __restrict__ in_pc,  // [b][65536][CIN] fp16
    const unsigned short* __restrict__ wb,     // [9][64][CIN] fp16
    const float* __restrict__ bias,
    const unsigned short* __restrict__ addh,   // fp16 [b][pix][64] addend (residual)
    const unsigned short* __restrict__ xh,     // fp16 [b][pix][64] (concat x)
    float* __restrict__ outf,                  // fp32 NCHW
    unsigned short* __restrict__ outb)         // fp16 [b][65536][64]
{
    __shared__ unsigned short smem[39168];     // 76.5 KB (max of both paths)

    const int tid = threadIdx.x;
    const int w   = tid >> 6;
    const int ln  = tid & 63;
    const int m   = ln & 15;    // outch-in-group for A; pixel-col for B/D
    const int q   = ln >> 4;    // quad
    const int b   = blockIdx.z;
    const int tx0 = blockIdx.x * 16, ty0 = blockIdx.y * 16;
    const size_t pixb = (size_t)b * PLANE;
    const bool interior = (blockIdx.x >= 1) && (blockIdx.x <= 14) &&
                          (blockIdx.y >= 1) && (blockIdx.y <= 14);

    f32x4 acc[4][4];
#pragma unroll
    for (int g = 0; g < 4; ++g)
#pragma unroll
        for (int p = 0; p < 4; ++p) acc[g][p] = (f32x4)0.f;

    if constexpr (CIN == 64) {
        // ---------- tap-group pipelined path ----------
        unsigned short* lds_in = smem;           // 324 px * 64 ch = 20736 halves
        unsigned short* wbuf0  = smem + 20736;   // 2 taps * 64 oc * 64 ch = 8192 halves
        unsigned short* wbuf1  = smem + 28928;   // 8192 halves

        // ---- stage FULL input halo once: 324 px x 64 ch; slot = part ^ (pix&7) ----
        if (interior) {
            const unsigned short* inb =
                in_pc + (pixb + (size_t)(ty0 - 1) * 256 + (tx0 - 1)) * 64;
#pragma unroll
            for (int it = 0; it < 10; ++it) {
                int u = it * 256 + tid;
                int pix = u >> 3, ps = u & 7;
                int part = ps ^ (pix & 7);
                int hy = pix / 18, hx = pix - hy * 18;
                gl16(inb + ((size_t)hy * 256 + hx) * 64 + part * 8,
                     &lds_in[(it * 256 + (tid & 192)) * 8]);
            }
            if (tid < 32) {   // tail: u = 2560..2591 (wave 0, lanes 0..31)
                int u = 2560 + tid;
                int pix = u >> 3, ps = u & 7;
                int part = ps ^ (pix & 7);
                int hy = pix / 18, hx = pix - hy * 18;
                gl16(inb + ((size_t)hy * 256 + hx) * 64 + part * 8,
                     &lds_in[2560 * 8]);
            }
        } else {
            for (int u = tid; u < 2592; u += 256) {
                int pix = u >> 3, part = u & 7;
                int hy = pix / 18, hx = pix - hy * 18;
                int gy = ty0 + hy - 1, gx = tx0 + hx - 1;
                uint4 val = make_uint4(0u, 0u, 0u, 0u);
                if ((unsigned)gy < 256u && (unsigned)gx < 256u)
                    val = *reinterpret_cast<const uint4*>(
                        in_pc + ((pixb + (size_t)gy * 256 + gx) * 64 + part * 8));
                int sl = part ^ (pix & 7);
                *reinterpret_cast<uint4*>(&lds_in[pix * 64 + sl * 8]) = val;
            }
        }

        // stage ntaps taps' weights (full 64 ch) starting at tap t0 into dst.
        // row = t_local*64 + oc (128 B), slot sl holds global part sl ^ (row&7).
        auto stage_w = [&](int t0, int ntaps, unsigned short* dst) {
            for (int it = 0; it < ntaps * 2; ++it) {
                int u = it * 256 + tid;
                int row = u >> 3, sl = u & 7;
                int part = sl ^ (row & 7);
                gl16(wb + ((size_t)((t0 + (row >> 6)) * 64 + (row & 63))) * 64 + part * 8,
                     &dst[(it * 256 + (tid & 192)) * 8]);
            }
        };

        stage_w(0, 2, wbuf0);
        __syncthreads();   // drain input + group-0 weights

#pragma unroll
        for (int gi = 0; gi < 5; ++gi) {
            const int t0 = gi * 2;
            const int nt = (gi == 4) ? 1 : 2;
            unsigned short* cw = (gi & 1) ? wbuf1 : wbuf0;
            if (gi < 4)   // prefetch next group's weights (hidden under MFMAs)
                stage_w((gi + 1) * 2, (gi + 1 == 4) ? 1 : 2, (gi & 1) ? wbuf0 : wbuf1);

#pragma unroll
            for (int tl = 0; tl < nt; ++tl) {
                const int t = t0 + tl;
                const int dy = t / 3, dx = t - dy * 3;
#pragma unroll
                for (int c2 = 0; c2 < 2; ++c2) {
                    f16x8 av[4], bv[4];
#pragma unroll
                    for (int g = 0; g < 4; ++g) {
                        int row = tl * 64 + g * 16 + m;
                        av[g] = *reinterpret_cast<const f16x8*>(
                            &cw[row * 64 + (((c2 * 4 + q) ^ (m & 7)) * 8)]);
                    }
#pragma unroll
                    for (int p = 0; p < 4; ++p) {
                        int hp = (w * 4 + p + dy) * 18 + m + dx;
                        bv[p] = *reinterpret_cast<const f16x8*>(
                            &lds_in[hp * 64 + (((c2 * 4 + q) ^ (hp & 7)) * 8)]);
                    }
#pragma unroll
                    for (int g = 0; g < 4; ++g)
#pragma unroll
                        for (int p = 0; p < 4; ++p)
                            acc[g][p] = __builtin_amdgcn_mfma_f32_16x16x32_f16(
                                av[g], bv[p], acc[g][p], 0, 0, 0);
                }
            }
            __syncthreads();   // drain next-group weights; last one protects epilogue
        }
    } else {
        // ---------- R7 path (CIN = 96): input dbuf + per-chunk weights ----------
        unsigned short* lds_w = smem + 20736;    // 9*64*32 = 18432 halves

        auto stage_in = [&](int c2s, unsigned short* dst) {
            if (interior) {
                const unsigned short* inb =
                    in_pc + (pixb + (size_t)(ty0 - 1) * 256 + (tx0 - 1)) * CIN + c2s * 32;
#pragma unroll
                for (int it = 0; it < 5; ++it) {
                    int u = it * 256 + tid;
                    int pix = u >> 2, ps = u & 3;
                    int part = ps ^ (pix & 3);
                    int hy = pix / 18, hx = pix - hy * 18;
                    gl16(inb + ((size_t)hy * 256 + hx) * CIN + part * 8,
                         &dst[(it * 256 + (tid & 192)) * 8]);
                }
                if (tid < 16) {
                    int u = 1280 + tid;
                    int pix = u >> 2, ps = u & 3;
                    int part = ps ^ (pix & 3);
                    int hy = pix / 18, hx = pix - hy * 18;
                    gl16(inb + ((size_t)hy * 256 + hx) * CIN + part * 8,
                         &dst[1280 * 8]);
                }
            } else {
                for (int u = tid; u < 1296; u += 256) {
                    int pix = u >> 2, part = u & 3;
                    int hy = pix / 18, hx = pix - hy * 18;
                    int gy = ty0 + hy - 1, gx = tx0 + hx - 1;
                    uint4 val = make_uint4(0u, 0u, 0u, 0u);
                    if ((unsigned)gy < 256u && (unsigned)gx < 256u)
                        val = *reinterpret_cast<const uint4*>(
                            in_pc + ((pixb + (size_t)gy * 256 + gx) * CIN + c2s * 32 + part * 8));
                    *reinterpret_cast<uint4*>(&dst[pix * 32 + ((part ^ (pix & 3)) * 8)]) = val;
                }
            }
        };
        auto stage_w = [&](int c2s) {
            const int oc = tid >> 2, ps = tid & 3;
            const int part = ps ^ (oc & 3);
            const unsigned short* wsrc = wb + (size_t)oc * CIN + c2s * 32 + part * 8;
#pragma unroll
            for (int t = 0; t < 9; ++t)
                gl16(wsrc + (size_t)t * 64 * CIN,
                     &lds_w[t * 2048 + (tid & 192) * 8]);
        };

        constexpr int NC = CIN / 32;
        stage_in(0, smem);
        stage_w(0);
        __syncthreads();

        for (int c2 = 0; c2 < NC; ++c2) {
            unsigned short* cbuf = (c2 & 1) ? smem + 10368 : smem;
            if (c2 + 1 < NC)
                stage_in(c2 + 1, ((c2 + 1) & 1) ? smem + 10368 : smem);

#pragma unroll
            for (int t = 0; t < 9; ++t) {
                const int dy = t / 3, dx = t - dy * 3;
                f16x8 av[4], bv[4];
#pragma unroll
                for (int g = 0; g < 4; ++g) {
                    int oc = g * 16 + m;
                    av[g] = *reinterpret_cast<const f16x8*>(
                        &lds_w[t * 2048 + oc * 32 + ((q ^ (oc & 3)) * 8)]);
                }
#pragma unroll
                for (int p = 0; p < 4; ++p) {
                    int hp = (w * 4 + p + dy) * 18 + m + dx;
                    bv[p] = *reinterpret_cast<const f16x8*>(
                        &cbuf[hp * 32 + ((q ^ (hp & 3)) * 8)]);
                }
#pragma unroll
                for (int g = 0; g < 4; ++g)
#pragma unroll
                    for (int p = 0; p < 4; ++p)
                        acc[g][p] = __builtin_amdgcn_mfma_f32_16x16x32_f16(
                            av[g], bv[p], acc[g][p], 0, 0, 0);
            }

            if (c2 + 1 < NC) {
                __syncthreads();
                stage_w(c2 + 1);
                __syncthreads();
            }
        }
        if (OUTB) __syncthreads();   // protect last chunk's LDS reads before overwrite
    }

    // ---------------- epilogue ----------------
    // D layout: row(outch-in-grp) = q*4+reg, col(pixel) = m
    const int colx = tx0 + m;
    float4 bvec[4];
    if (BIAS) {
#pragma unroll
        for (int g = 0; g < 4; ++g)
            bvec[g] = *reinterpret_cast<const float4*>(bias + g * 16 + q * 4);
    }

#pragma unroll
    for (int g = 0; g < 4; ++g) {
#pragma unroll
        for (int p = 0; p < 4; ++p) {
            const int prow = w * 4 + p;
            const int gy   = ty0 + prow;
            const size_t pixg = pixb + (size_t)gy * 256 + colx;
            const int oc0 = g * 16 + q * 4;
            ushort4 a4, x4;
            if (ADDF) a4 = *reinterpret_cast<const ushort4*>(addh + pixg * 64 + oc0);
            if (ADDX || MULX) x4 = *reinterpret_cast<const ushort4*>(xh + pixg * 64 + oc0);
            float vals[4];
#pragma unroll
            for (int r = 0; r < 4; ++r) {
                float v = acc[g][p][r];
                if (BIAS) v += reinterpret_cast<const float*>(&bvec[g])[r];
                if (LEAKY) v = (v >= 0.f) ? v : 0.2f * v;
                if (ADDF) v += h2f(reinterpret_cast<const unsigned short*>(&a4)[r]);
                if (ADDX) v += h2f(reinterpret_cast<const unsigned short*>(&x4)[r]);
                if (MULX) v *= h2f(reinterpret_cast<const unsigned short*>(&x4)[r]);
                if (OUTF)
                    outf[((size_t)(b * 64 + oc0 + r)) * PLANE + (size_t)gy * 256 + colx] = v;
                vals[r] = v;
            }
            if (OUTB) {  // stage to LDS for [pix][64] vector store
                ushort4 pk;
                pk.x = f2h(vals[0]); pk.y = f2h(vals[1]);
                pk.z = f2h(vals[2]); pk.w = f2h(vals[3]);
                int pix   = prow * 16 + m;
                int part8 = g * 4 + q;
                int p16   = (part8 >> 1) ^ (pix & 7);
                *reinterpret_cast<ushort4*>(&smem[pix * 64 + p16 * 8 + (part8 & 1) * 4]) = pk;
            }
        }
    }
    if (OUTB) {
        __syncthreads();
        for (int u = tid; u < 2048; u += 256) {
            int pix = u >> 3, p16 = u & 7;
            uint4 val = *reinterpret_cast<const uint4*>(
                &smem[pix * 64 + ((p16 ^ (pix & 7)) * 8)]);
            int gy = ty0 + (pix >> 4), gx = tx0 + (pix & 15);
            *reinterpret_cast<uint4*>(
                &outb[(pixb + (size_t)gy * 256 + gx) * 64 + p16 * 8]) = val;
        }
    }
}

// ---------------- local similarity (LDS-tiled, fp16 dot2, di-grouped) ----------------
// att[b][pix][p] = dot64(q[pix], k[pix+(di-4,dj-4)]), p=di*9+dj; ch 81..95 = 0.
// Round-2 version verbatim (70 us verified).
__global__ __launch_bounds__(256)
void local_sim(
    const unsigned short* __restrict__ qh, const unsigned short* __restrict__ kh,
    unsigned short* __restrict__ att)
{
    __shared__ unsigned short lds_k[576 * 64];   // 24*24 px x 64ch fp16 = 73.7 KB

    const int tid = threadIdx.x;
    const int tx = tid & 15, ty = tid >> 4;
    const int bx = blockIdx.x * 16, by = blockIdx.y * 16;
    const int b  = blockIdx.z;
    const size_t pixb = (size_t)b * PLANE;
    const bool interior = (blockIdx.x >= 1) && (blockIdx.x <= 14) &&
                          (blockIdx.y >= 1) && (blockIdx.y <= 14);

    // ---- stage K halo 24x24 x 64ch once; slot = part ^ ((pix ^ pix>>3) & 7) ----
    if (interior) {
        const unsigned short* kb =
            kh + (pixb + (size_t)(by - 4) * 256 + (bx - 4)) * 64;
#pragma unroll
        for (int it = 0; it < 18; ++it) {
            int u = it * 256 + tid;
            int pix = u >> 3, sl = u & 7;
            int part = sl ^ ((pix ^ (pix >> 3)) & 7);
            int hy = pix / 24, hx = pix - hy * 24;
            gl16(kb + ((size_t)hy * 256 + hx) * 64 + part * 8,
                 &lds_k[(it * 256 + (tid & 192)) * 8]);
        }
    } else {
        for (int u = tid; u < 4608; u += 256) {
            int pix = u >> 3, part = u & 7;
            int hy = pix / 24, hx = pix - hy * 24;
            int gy = by + hy - 4, gx = bx + hx - 4;
            uint4 val = make_uint4(0u, 0u, 0u, 0u);
            if ((unsigned)gy < 256u && (unsigned)gx < 256u)
                val = *reinterpret_cast<const uint4*>(
                    kh + ((pixb + (size_t)gy * 256 + gx) * 64 + part * 8));
            int sl = part ^ ((pix ^ (pix >> 3)) & 7);
            *reinterpret_cast<uint4*>(&lds_k[pix * 64 + sl * 8]) = val;
        }
    }
    __syncthreads();

    const unsigned short* qbase = qh + (pixb + (size_t)(by + ty) * 256 + bx + tx) * 64;
    unsigned short* op = att + (pixb + (size_t)(by + ty) * 256 + bx + tx) * 96;

    uint4 qv[8];
#pragma unroll
    for (int j = 0; j < 8; ++j)
        qv[j] = *reinterpret_cast<const uint4*>(qbase + j * 8);

#pragma unroll
    for (int g = 0; g < 3; ++g) {
        float acc[27];
#pragma unroll
        for (int i = 0; i < 27; ++i) acc[i] = 0.f;

#pragma unroll
        for (int dil = 0; dil < 3; ++dil) {
            const int hrow = (ty + g * 3 + dil) * 24 + tx;
#pragma unroll
            for (int dj = 0; dj < 9; ++dj) {
                const int hp = hrow + dj;
                const int gs = (hp ^ (hp >> 3)) & 7;
                float s = acc[dil * 9 + dj];
#pragma unroll
                for (int part = 0; part < 8; ++part) {
                    const uint4 kv = *reinterpret_cast<const uint4*>(
                        &lds_k[hp * 64 + ((part ^ gs) * 8)]);
                    s = dot2h(qv[part].x, kv.x, s);
                    s = dot2h(qv[part].y, kv.y, s);
                    s = dot2h(qv[part].z, kv.z, s);
                    s = dot2h(qv[part].w, kv.w, s);
                }
                acc[dil * 9 + dj] = s;
            }
        }

        // ---- store this group's 27 fp16 values at op + g*27 ----
        unsigned short* o = op + g * 27;
        if (g == 0) {
            uint4 A = {pack2h(acc[0], acc[1]),  pack2h(acc[2], acc[3]),
                       pack2h(acc[4], acc[5]),  pack2h(acc[6], acc[7])};
            uint4 B = {pack2h(acc[8], acc[9]),  pack2h(acc[10], acc[11]),
                       pack2h(acc[12], acc[13]), pack2h(acc[14], acc[15])};
            uint2 C = {pack2h(acc[16], acc[17]), pack2h(acc[18], acc[19])};
            uint2 D = {pack2h(acc[20], acc[21]), pack2h(acc[22], acc[23])};
            *reinterpret_cast<uint4*>(o)      = A;
            *reinterpret_cast<uint4*>(o + 8)  = B;
            *reinterpret_cast<uint2*>(o + 16) = C;
            *reinterpret_cast<uint2*>(o + 20) = D;
            *reinterpret_cast<unsigned*>(o + 24) = pack2h(acc[24], acc[25]);
            o[26] = f2h(acc[26]);
        } else if (g == 1) {
            o[0] = f2h(acc[0]);
            *reinterpret_cast<unsigned*>(o + 1) = pack2h(acc[1], acc[2]);
            *reinterpret_cast<unsigned*>(o + 3) = pack2h(acc[3], acc[4]);
            uint4 A = {pack2h(acc[5], acc[6]),   pack2h(acc[7], acc[8]),
                       pack2h(acc[9], acc[10]),  pack2h(acc[11], acc[12])};
            uint4 B = {pack2h(acc[13], acc[14]), pack2h(acc[15], acc[16]),
                       pack2h(acc[17], acc[18]), pack2h(acc[19], acc[20])};
            *reinterpret_cast<uint4*>(o + 5)  = A;
            *reinterpret_cast<uint4*>(o + 13) = B;
            uint2 C = {pack2h(acc[21], acc[22]), pack2h(acc[23], acc[24])};
            *reinterpret_cast<uint2*>(o + 21) = C;
            *reinterpret_cast<unsigned*>(o + 25) = pack2h(acc[25], acc[26]);
        } else {
            *reinterpret_cast<unsigned*>(o) = pack2h(acc[0], acc[1]);
            uint4 A = {pack2h(acc[2], acc[3]),   pack2h(acc[4], acc[5]),
                       pack2h(acc[6], acc[7]),   pack2h(acc[8], acc[9])};
            uint4 B = {pack2h(acc[10], acc[11]), pack2h(acc[12], acc[13]),
                       pack2h(acc[14], acc[15]), pack2h(acc[16], acc[17])};
            *reinterpret_cast<uint4*>(o + 2)  = A;
            *reinterpret_cast<uint4*>(o + 10) = B;
            uint2 C = {pack2h(acc[18], acc[19]), pack2h(acc[20], acc[21])};
            *reinterpret_cast<uint2*>(o + 18) = C;
            *reinterpret_cast<unsigned*>(o + 22) = pack2h(acc[22], acc[23]);
            *reinterpret_cast<unsigned*>(o + 24) = pack2h(acc[24], acc[25]);
            o[26] = f2h(acc[26]);
        }
    }

    // zero channels 81..95
    op[81] = 0;
    *reinterpret_cast<unsigned*>(op + 82) = 0u;
    uint2 z2 = {0u, 0u};
    uint4 z4 = {0u, 0u, 0u, 0u};
    *reinterpret_cast<uint2*>(op + 84) = z2;
    *reinterpret_cast<uint4*>(op + 88) = z4;
}

// ---------------- pack x: fp32 NCHW old/new -> fp16 [b][pix][64] ----------------
__global__ __launch_bounds__(256) void pack_x(
    const float* __restrict__ old_, const float* __restrict__ new_,
    unsigned short* __restrict__ xb)
{
    __shared__ unsigned short lds[256 * 64];
    const int tid = threadIdx.x;
    const int b = blockIdx.y;
    const size_t pixbase = (size_t)blockIdx.x * 256;
#pragma unroll
    for (int cg = 0; cg < 8; ++cg) {
        unsigned pk[4];
#pragma unroll
        for (int h = 0; h < 4; ++h) {
            int c0 = cg * 8 + h * 2;
            const float* s0 = (c0 < 32) ? old_ : new_;
            const float* s1 = ((c0 + 1) < 32) ? old_ : new_;
            float f0 = s0[((size_t)b * 32 + (c0 & 31)) * PLANE + pixbase + tid];
            float f1 = s1[((size_t)b * 32 + ((c0 + 1) & 31)) * PLANE + pixbase + tid];
            pk[h] = pack2h(f0, f1);
        }
        int p16 = cg ^ (tid & 7);
        uint4 v; v.x = pk[0]; v.y = pk[1]; v.z = pk[2]; v.w = pk[3];
        *reinterpret_cast<uint4*>(&lds[tid * 64 + p16 * 8]) = v;
    }
    __syncthreads();
    for (int r = 0; r < 8; ++r) {
        int u = r * 256 + tid;
        int pix = u >> 3, p16 = u & 7;
        uint4 v = *reinterpret_cast<const uint4*>(&lds[pix * 64 + ((p16 ^ (pix & 7)) * 8)]);
        *reinterpret_cast<uint4*>(
            &xb[((size_t)b * PLANE + pixbase + pix) * 64 + p16 * 8]) = v;
    }
}

// ---------------- weight prep: fp32 OIHW -> fp16 [9][64][CIN] ----------------
__global__ void prep_wstd(const float* __restrict__ wq, const float* __restrict__ wk,
                          const float* __restrict__ wo1, const float* __restrict__ wo2,
                          const float* __restrict__ rw1, const float* __restrict__ rw2,
                          unsigned short* __restrict__ wstd)
{
    const int c = blockIdx.y;  // 0..19
    const float* src;
    if (c == 0) src = wq;
    else if (c == 1) src = wk;
    else if (c == 2) src = wo1;
    else if (c == 3) src = wo2;
    else if (c < 12) src = rw1 + (size_t)(c - 4) * 36864;
    else src = rw2 + (size_t)(c - 12) * 36864;
    int idx = blockIdx.x * 256 + threadIdx.x;  // 0..4095
    int o = idx >> 6, i = idx & 63;
    const float* s = src + (size_t)(o * 64 + i) * 9;
    unsigned short* d = wstd + (size_t)c * 36864 + (size_t)o * 64 + i;
#pragma unroll
    for (int t = 0; t < 9; ++t) d[(size_t)t * 4096] = f2h(s[t]);
}

__global__ void prep_wv(const float* __restrict__ wv, unsigned short* __restrict__ wv96)
{
    int idx = blockIdx.x * 256 + threadIdx.x;  // < 6144
    int o = idx / 96, i = idx - o * 96;
    unsigned short* d = wv96 + (size_t)o * 96 + i;
    if (i < 81) {
        const float* s = wv + (size_t)(o * 81 + i) * 9;
#pragma unroll
        for (int t = 0; t < 9; ++t) d[(size_t)t * 6144] = f2h(s[t]);
    } else {
#pragma unroll
        for (int t = 0; t < 9; ++t) d[(size_t)t * 6144] = 0;
    }
}

extern "C" void kernel_launch(void* const* d_in, const int* in_sizes, int n_in,
                              void* d_out, int out_size, void* d_ws, size_t ws_size,
                              hipStream_t stream)
{
    const float* old_ = (const float*)d_in[0];
    const float* new_ = (const float*)d_in[1];
    const float* wq  = (const float*)d_in[2];  const float* bq  = (const float*)d_in[3];
    const float* wk  = (const float*)d_in[4];  const float* bk  = (const float*)d_in[5];
    const float* wv  = (const float*)d_in[6];  const float* bv  = (const float*)d_in[7];
    const float* wo1 = (const float*)d_in[8];  const float* bo1 = (const float*)d_in[9];
    const float* rw1 = (const float*)d_in[10]; const float* rw2 = (const float*)d_in[11];
    const float* wo2 = (const float*)d_in[12]; const float* bo2 = (const float*)d_in[13];
    float* out = (float*)d_out;

    char* ws = (char*)d_ws;
    // X : xh fp16 (32 MiB, persistent)
    // P1: q -> y_a (32 MiB) ; P2: k -> xv -> h1 (32 MiB) ; P3: att96(48) -> y_b
    unsigned short* X   = (unsigned short*)(ws);
    unsigned short* P1  = (unsigned short*)(ws + 33554432ull);
    unsigned short* P2  = (unsigned short*)(ws + 67108864ull);
    unsigned short* P3  = (unsigned short*)(ws + 100663296ull);
    unsigned short* wst = (unsigned short*)(ws + 150994944ull);   // 20*36864 fp16
    unsigned short* wv96= (unsigned short*)(ws + 152469504ull);   // 9*64*96 fp16

    const dim3 cgrid(16, 16, 4), cblk(256);

    prep_wstd<<<dim3(16, 20), 256, 0, stream>>>(wq, wk, wo1, wo2, rw1, rw2, wst);
    prep_wv<<<dim3(24), 256, 0, stream>>>(wv, wv96);
    pack_x<<<dim3(256, 4), 256, 0, stream>>>(old_, new_, X);

    // q = conv(x, wq, bq); k = conv(x, wk, bk)
    conv_mfma<64, true, false, false, false, false, false, true>
        <<<cgrid, cblk, 0, stream>>>(X, wst + 0ull * 36864, bq, nullptr, nullptr, nullptr, P1);
    conv_mfma<64, true, false, false, false, false, false, true>
        <<<cgrid, cblk, 0, stream>>>(X, wst + 1ull * 36864, bk, nullptr, nullptr, nullptr, P2);
    // att (fp16, 96ch padded)
    local_sim<<<cgrid, cblk, 0, stream>>>(P1, P2, P3);
    // xv = x * (conv(att, wv) + bv)   [MULX fused]
    conv_mfma<96, true, false, false, false, true, false, true>
        <<<cgrid, cblk, 0, stream>>>(P3, wv96, bv, nullptr, X, nullptr, P2);
    // y0 = conv(xv, wo1, bo1) -> P1
    conv_mfma<64, true, false, false, false, false, false, true>
        <<<cgrid, cblk, 0, stream>>>(P2, wst + 2ull * 36864, bo1, nullptr, nullptr, nullptr, P1);
    // 8 ResBlocks; y ping-pong P1 <-> P3, h1 in P2; residual add fused in conv2
    for (int i = 0; i < 8; ++i) {
        unsigned short* ysrc = (i & 1) ? P3 : P1;
        unsigned short* ydst = (i & 1) ? P1 : P3;
        conv_mfma<64, false, true, false, false, false, false, true>
            <<<cgrid, cblk, 0, stream>>>(ysrc, wst + (size_t)(4 + i) * 36864, nullptr,
                                         nullptr, nullptr, nullptr, P2);
        conv_mfma<64, false, false, true, false, false, false, true>
            <<<cgrid, cblk, 0, stream>>>(P2, wst + (size_t)(12 + i) * 36864, nullptr,
                                         ysrc, nullptr, nullptr, ydst);
    }
    // out = conv(y, wo2, bo2) + x   [ADDX fused]; final y in P1
    conv_mfma<64, true, false, false, true, false, true, false>
        <<<cgrid, cblk, 0, stream>>>(P1, wst + 3ull * 36864, bo2, nullptr, X, out, nullptr);
}

// Round 9
// 795.730 us; speedup vs baseline: 1.0550x; 1.0550x over previous
//
#include <hip/hip_runtime.h>
#include <hip/hip_bf16.h>

// SRPBlock forward — fp16 end-to-end MFMA implicit-GEMM convs + LDS-tiled local attention.
// x=concat(old,new) [4,64,256,256] fp32 NCHW inputs; all activations flow as fp16
// [b][pix][ch] (channel-contiguous); fp32 accumulate everywhere; final out fp32 NCHW.
//
// This revision (R7 = 833 us anchor + ResBlock fusion):
//  * NEW res_fused kernel: conv1+leaky+conv2+residual in ONE kernel per ResBlock.
//    conv1 computed on the 18x18 h1 halo (21 px-groups, 6/wave balanced), h1 kept
//    in LDS -> eliminates 8 dispatches and 8x(32MiB write + 32MiB read) of h1.
//    LDS 76.5 KB (same as R7), 2 blocks/CU. Bit-identical numerics (same chunk/tap
//    order, h1 via fp16, boundary h1 zeroed to match conv2 zero-padding).
//  * conv_mfma (q,k,xv,y0,out) and local_sim: R7 verbatim.

#define HH 256
#define WW 256
#define PLANE 65536

typedef _Float16 f16x8 __attribute__((ext_vector_type(8)));
typedef float    f32x4 __attribute__((ext_vector_type(4)));
typedef _Float16 h2    __attribute__((ext_vector_type(2)));

__device__ __forceinline__ unsigned short f2h(float f) {
    _Float16 h = (_Float16)f;                  // v_cvt_f16_f32 (RNE)
    return __builtin_bit_cast(unsigned short, h);
}
__device__ __forceinline__ float h2f(unsigned short u) {
    return (float)__builtin_bit_cast(_Float16, u);
}
__device__ __forceinline__ unsigned pack2h(float a, float b) {
    return (unsigned)f2h(a) | ((unsigned)f2h(b) << 16);
}
__device__ __forceinline__ float dot2h(unsigned a, unsigned b, float c) {
#if __has_builtin(__builtin_amdgcn_fdot2)
    return __builtin_amdgcn_fdot2(__builtin_bit_cast(h2, a),
                                  __builtin_bit_cast(h2, b), c, false);
#else
    h2 av = __builtin_bit_cast(h2, a), bv = __builtin_bit_cast(h2, b);
    return fmaf((float)av.x, (float)bv.x, fmaf((float)av.y, (float)bv.y, c));
#endif
}

// async 16B global -> LDS. LDS dest is wave-uniform base + lane*16 (linear);
// per-lane swizzling must be applied to the GLOBAL source address.
__device__ __forceinline__ void gl16(const unsigned short* g, unsigned short* l) {
    __builtin_amdgcn_global_load_lds(
        (const __attribute__((address_space(1))) unsigned int*)(g),
        (__attribute__((address_space(3))) unsigned int*)(l),
        16, 0, 0);
}

// ---------------- conv3x3 (pad=1, Cout=64) via MFMA 16x16x32 f16 ----------------
// R7 version: input dbuf prefetch, weights per chunk. block=256, tile 16x16.
template <int CIN, bool BIAS, bool LEAKY, bool ADDF, bool ADDX, bool MULX, bool OUTF, bool OUTB>
__global__ __launch_bounds__(256, 2) void conv_mfma(
    const unsigned short* __restrict__ in_pc,  // [b][65536][CIN] fp16
    const unsigned short* __restrict__ wb,     // [9][64][CIN] fp16
    const float* __restrict__ bias,
    const unsigned short* __restrict__ addh,   // fp16 [b][pix][64] addend (residual)
    const unsigned short* __restrict__ xh,     // fp16 [b][pix][64] (concat x)
    float* __restrict__ outf,                  // fp32 NCHW
    unsigned short* __restrict__ outb)         // fp16 [b][65536][64]
{
    __shared__ unsigned short smem[39168];     // 76.5 KB: in0 | in1 | w
    unsigned short* lds_w = smem + 20736;      // 9*64*32 = 18432 halves

    const int tid = threadIdx.x;
    const int w   = tid >> 6;
    const int ln  = tid & 63;
    const int m   = ln & 15;    // outch-in-group for A; pixel-col for B/D
    const int q   = ln >> 4;    // quad
    const int b   = blockIdx.z;
    const int tx0 = blockIdx.x * 16, ty0 = blockIdx.y * 16;
    const size_t pixb = (size_t)b * PLANE;
    const bool interior = (blockIdx.x >= 1) && (blockIdx.x <= 14) &&
                          (blockIdx.y >= 1) && (blockIdx.y <= 14);

    auto stage_in = [&](int c2s, unsigned short* dst) {
        if (interior) {
            const unsigned short* inb =
                in_pc + (pixb + (size_t)(ty0 - 1) * 256 + (tx0 - 1)) * CIN + c2s * 32;
#pragma unroll
            for (int it = 0; it < 5; ++it) {
                int u = it * 256 + tid;
                int pix = u >> 2, ps = u & 3;
                int part = ps ^ (pix & 3);
                int hy = pix / 18, hx = pix - hy * 18;
                gl16(inb + ((size_t)hy * 256 + hx) * CIN + part * 8,
                     &dst[(it * 256 + (tid & 192)) * 8]);
            }
            if (tid < 16) {   // tail: u = 1280..1295
                int u = 1280 + tid;
                int pix = u >> 2, ps = u & 3;
                int part = ps ^ (pix & 3);
                int hy = pix / 18, hx = pix - hy * 18;
                gl16(inb + ((size_t)hy * 256 + hx) * CIN + part * 8,
                     &dst[1280 * 8]);
            }
        } else {
            for (int u = tid; u < 1296; u += 256) {
                int pix = u >> 2, part = u & 3;
                int hy = pix / 18, hx = pix - hy * 18;
                int gy = ty0 + hy - 1, gx = tx0 + hx - 1;
                uint4 val = make_uint4(0u, 0u, 0u, 0u);
                if ((unsigned)gy < 256u && (unsigned)gx < 256u)
                    val = *reinterpret_cast<const uint4*>(
                        in_pc + ((pixb + (size_t)gy * 256 + gx) * CIN + c2s * 32 + part * 8));
                *reinterpret_cast<uint4*>(&dst[pix * 32 + ((part ^ (pix & 3)) * 8)]) = val;
            }
        }
    };
    auto stage_w = [&](int c2s) {
        const int oc = tid >> 2, ps = tid & 3;
        const int part = ps ^ (oc & 3);
        const unsigned short* wsrc = wb + (size_t)oc * CIN + c2s * 32 + part * 8;
#pragma unroll
        for (int t = 0; t < 9; ++t)
            gl16(wsrc + (size_t)t * 64 * CIN,
                 &lds_w[t * 2048 + (tid & 192) * 8]);
    };

    f32x4 acc[4][4];
#pragma unroll
    for (int g = 0; g < 4; ++g)
#pragma unroll
        for (int p = 0; p < 4; ++p) acc[g][p] = (f32x4)0.f;

    constexpr int NC = CIN / 32;
    stage_in(0, smem);
    stage_w(0);
    __syncthreads();

    for (int c2 = 0; c2 < NC; ++c2) {
        unsigned short* cbuf = (c2 & 1) ? smem + 10368 : smem;
        if (c2 + 1 < NC)
            stage_in(c2 + 1, ((c2 + 1) & 1) ? smem + 10368 : smem);

#pragma unroll
        for (int t = 0; t < 9; ++t) {
            const int dy = t / 3, dx = t - dy * 3;
            f16x8 av[4], bv[4];
#pragma unroll
            for (int g = 0; g < 4; ++g) {
                int oc = g * 16 + m;
                av[g] = *reinterpret_cast<const f16x8*>(
                    &lds_w[t * 2048 + oc * 32 + ((q ^ (oc & 3)) * 8)]);
            }
#pragma unroll
            for (int p = 0; p < 4; ++p) {
                int hp = (w * 4 + p + dy) * 18 + m + dx;
                bv[p] = *reinterpret_cast<const f16x8*>(
                    &cbuf[hp * 32 + ((q ^ (hp & 3)) * 8)]);
            }
#pragma unroll
            for (int g = 0; g < 4; ++g)
#pragma unroll
                for (int p = 0; p < 4; ++p)
                    acc[g][p] = __builtin_amdgcn_mfma_f32_16x16x32_f16(
                        av[g], bv[p], acc[g][p], 0, 0, 0);
        }

        if (c2 + 1 < NC) {
            __syncthreads();
            stage_w(c2 + 1);
            __syncthreads();
        }
    }

    // epilogue
    const int colx = tx0 + m;
    float4 bvec[4];
    if (BIAS) {
#pragma unroll
        for (int g = 0; g < 4; ++g)
            bvec[g] = *reinterpret_cast<const float4*>(bias + g * 16 + q * 4);
    }
    if (OUTB) __syncthreads();

#pragma unroll
    for (int g = 0; g < 4; ++g) {
#pragma unroll
        for (int p = 0; p < 4; ++p) {
            const int prow = w * 4 + p;
            const int gy   = ty0 + prow;
            const size_t pixg = pixb + (size_t)gy * 256 + colx;
            const int oc0 = g * 16 + q * 4;
            ushort4 a4, x4;
            if (ADDF) a4 = *reinterpret_cast<const ushort4*>(addh + pixg * 64 + oc0);
            if (ADDX || MULX) x4 = *reinterpret_cast<const ushort4*>(xh + pixg * 64 + oc0);
            float vals[4];
#pragma unroll
            for (int r = 0; r < 4; ++r) {
                float v = acc[g][p][r];
                if (BIAS) v += reinterpret_cast<const float*>(&bvec[g])[r];
                if (LEAKY) v = (v >= 0.f) ? v : 0.2f * v;
                if (ADDF) v += h2f(reinterpret_cast<const unsigned short*>(&a4)[r]);
                if (ADDX) v += h2f(reinterpret_cast<const unsigned short*>(&x4)[r]);
                if (MULX) v *= h2f(reinterpret_cast<const unsigned short*>(&x4)[r]);
                if (OUTF)
                    outf[((size_t)(b * 64 + oc0 + r)) * PLANE + (size_t)gy * 256 + colx] = v;
                vals[r] = v;
            }
            if (OUTB) {
                ushort4 pk;
                pk.x = f2h(vals[0]); pk.y = f2h(vals[1]);
                pk.z = f2h(vals[2]); pk.w = f2h(vals[3]);
                int pix   = prow * 16 + m;
                int part8 = g * 4 + q;
                int p16   = (part8 >> 1) ^ (pix & 7);
                *reinterpret_cast<ushort4*>(&smem[pix * 64 + p16 * 8 + (part8 & 1) * 4]) = pk;
            }
        }
    }
    if (OUTB) {
        __syncthreads();
        for (int u = tid; u < 2048; u += 256) {
            int pix = u >> 3, p16 = u & 7;
            uint4 val = *reinterpret_cast<const uint4*>(
                &smem[pix * 64 + ((p16 ^ (pix & 7)) * 8)]);
            int gy = ty0 + (pix >> 4), gx = tx0 + (pix & 15);
            *reinterpret_cast<uint4*>(
                &outb[(pixb + (size_t)gy * 256 + gx) * 64 + p16 * 8]) = val;
        }
    }
}

// ---------------- fused ResBlock: y + conv2(leaky(conv1(y))) ----------------
// Output tile 16x16; h1 computed on the 18x18 halo in-block and kept in LDS.
// conv1: y halo 20x20 staged per 32-ch chunk (12800 halves in region Y) + w1 chunk
// (region W); 21 px-groups balanced 6/wave (strided w+4j, shared group 20).
// h1 [324 px][64ch] then occupies region Y (20736 halves exactly); conv2 reads it
// with slot (c2*4+q)^(pix&7); w2 chunks through region W. Residual read from yin.
__global__ __launch_bounds__(256, 2) void res_fused(
    const unsigned short* __restrict__ yin,   // [b][65536][64] fp16
    const unsigned short* __restrict__ w1,    // [9][64][64] fp16
    const unsigned short* __restrict__ w2,    // [9][64][64] fp16
    unsigned short* __restrict__ yout)        // [b][65536][64] fp16
{
    __shared__ unsigned short smem[39168];    // regionY 20736 | regionW 18432
    unsigned short* lds_w = smem + 20736;

    const int tid = threadIdx.x;
    const int w   = tid >> 6;
    const int ln  = tid & 63;
    const int m   = ln & 15;
    const int q   = ln >> 4;
    const int b   = blockIdx.z;
    const int tx0 = blockIdx.x * 16, ty0 = blockIdx.y * 16;
    const size_t pixb = (size_t)b * PLANE;
    const bool interior = (blockIdx.x >= 1) && (blockIdx.x <= 14) &&
                          (blockIdx.y >= 1) && (blockIdx.y <= 14);

    // per-j h1 pixel coords: pix = g*16+m, g = w+4j (j<5) else 20 (computed by all,
    // written by wave 0 only)
    int jr[6], jc[6];
#pragma unroll
    for (int j = 0; j < 6; ++j) {
        int g = (j < 5) ? (w + 4 * j) : 20;
        int pix = g * 16 + m;
        jr[j] = pix / 18;
        jc[j] = pix - jr[j] * 18;
    }

    // stage y halo chunk: 400 px (20x20, origin ty0-2,tx0-2) x 32 ch into region Y
    auto stage_y = [&](int c2s) {
        if (interior) {
            const unsigned short* inb =
                yin + (pixb + (size_t)(ty0 - 2) * 256 + (tx0 - 2)) * 64 + c2s * 32;
#pragma unroll
            for (int it = 0; it < 6; ++it) {
                int u = it * 256 + tid;
                int pix = u >> 2, ps = u & 3;
                int part = ps ^ (pix & 3);
                int hy = pix / 20, hx = pix - hy * 20;
                gl16(inb + ((size_t)hy * 256 + hx) * 64 + part * 8,
                     &smem[(it * 256 + (tid & 192)) * 8]);
            }
            if (tid < 64) {   // tail: u = 1536..1599 (wave 0)
                int u = 1536 + tid;
                int pix = u >> 2, ps = u & 3;
                int part = ps ^ (pix & 3);
                int hy = pix / 20, hx = pix - hy * 20;
                gl16(inb + ((size_t)hy * 256 + hx) * 64 + part * 8,
                     &smem[1536 * 8]);
            }
        } else {
            for (int u = tid; u < 1600; u += 256) {
                int pix = u >> 2, part = u & 3;
                int hy = pix / 20, hx = pix - hy * 20;
                int gy = ty0 + hy - 2, gx = tx0 + hx - 2;
                uint4 val = make_uint4(0u, 0u, 0u, 0u);
                if ((unsigned)gy < 256u && (unsigned)gx < 256u)
                    val = *reinterpret_cast<const uint4*>(
                        yin + ((pixb + (size_t)gy * 256 + gx) * 64 + c2s * 32 + part * 8));
                *reinterpret_cast<uint4*>(&smem[pix * 32 + ((part ^ (pix & 3)) * 8)]) = val;
            }
        }
    };
    auto stage_w = [&](const unsigned short* wsrcb, int c2s) {
        const int oc = tid >> 2, ps = tid & 3;
        const int part = ps ^ (oc & 3);
        const unsigned short* wsrc = wsrcb + (size_t)oc * 64 + c2s * 32 + part * 8;
#pragma unroll
        for (int t = 0; t < 9; ++t)
            gl16(wsrc + (size_t)t * 64 * 64, &lds_w[t * 2048 + (tid & 192) * 8]);
    };

    // ---- conv1: h1 = leaky(conv(y, w1)) on 18x18 halo ----
    f32x4 acc1[6][4];
#pragma unroll
    for (int j = 0; j < 6; ++j)
#pragma unroll
        for (int g4 = 0; g4 < 4; ++g4) acc1[j][g4] = (f32x4)0.f;

    for (int c2 = 0; c2 < 2; ++c2) {
        if (c2) __syncthreads();           // previous chunk's reads complete
        stage_y(c2);
        stage_w(w1, c2);
        __syncthreads();

#pragma unroll
        for (int t = 0; t < 9; ++t) {
            const int dy = t / 3, dx = t - dy * 3;
            f16x8 av[4];
#pragma unroll
            for (int g4 = 0; g4 < 4; ++g4) {
                int oc = g4 * 16 + m;
                av[g4] = *reinterpret_cast<const f16x8*>(
                    &lds_w[t * 2048 + oc * 32 + ((q ^ (oc & 3)) * 8)]);
            }
#pragma unroll
            for (int j = 0; j < 6; ++j) {
                int ypix = (jr[j] + dy) * 20 + jc[j] + dx;
                f16x8 bv = *reinterpret_cast<const f16x8*>(
                    &smem[ypix * 32 + ((q ^ (ypix & 3)) * 8)]);
#pragma unroll
                for (int g4 = 0; g4 < 4; ++g4)
                    acc1[j][g4] = __builtin_amdgcn_mfma_f32_16x16x32_f16(
                        av[g4], bv, acc1[j][g4], 0, 0, 0);
            }
        }
    }

    // ---- h1 -> LDS region Y ([pix][64], slot part^(pix&7)); stage w2 chunk 0 ----
    __syncthreads();                        // all conv1 LDS reads done
    stage_w(w2, 0);
#pragma unroll
    for (int j = 0; j < 6; ++j) {
        const int g = (j < 5) ? (w + 4 * j) : 20;
        const int pix = g * 16 + m;
        const bool wr = (j < 5) || (w == 0 && m < 4);
        const int gy = ty0 - 1 + jr[j], gx = tx0 - 1 + jc[j];
        const bool ok = ((unsigned)gy < 256u) && ((unsigned)gx < 256u);
        if (wr) {
#pragma unroll
            for (int g4 = 0; g4 < 4; ++g4) {
                ushort4 pk;
#pragma unroll
                for (int r = 0; r < 4; ++r) {
                    float v = acc1[j][g4][r];
                    v = (v >= 0.f) ? v : 0.2f * v;
                    reinterpret_cast<unsigned short*>(&pk)[r] = ok ? f2h(v) : (unsigned short)0;
                }
                int part8 = g4 * 2 + (q >> 1);
                *reinterpret_cast<ushort4*>(
                    &smem[pix * 64 + ((part8 ^ (pix & 7)) * 8) + (q & 1) * 4]) = pk;
            }
        }
    }
    __syncthreads();                        // h1 writes + w2 chunk-0 drained

    // ---- conv2: acc2 = conv(h1, w2) ----
    f32x4 acc2[4][4];
#pragma unroll
    for (int g4 = 0; g4 < 4; ++g4)
#pragma unroll
        for (int p = 0; p < 4; ++p) acc2[g4][p] = (f32x4)0.f;

    for (int c2 = 0; c2 < 2; ++c2) {
        if (c2) {
            __syncthreads();
            stage_w(w2, 1);
            __syncthreads();
        }
#pragma unroll
        for (int t = 0; t < 9; ++t) {
            const int dy = t / 3, dx = t - dy * 3;
            f16x8 av[4], bv[4];
#pragma unroll
            for (int g4 = 0; g4 < 4; ++g4) {
                int oc = g4 * 16 + m;
                av[g4] = *reinterpret_cast<const f16x8*>(
                    &lds_w[t * 2048 + oc * 32 + ((q ^ (oc & 3)) * 8)]);
            }
#pragma unroll
            for (int p = 0; p < 4; ++p) {
                int hp = (w * 4 + p + dy) * 18 + m + dx;
                bv[p] = *reinterpret_cast<const f16x8*>(
                    &smem[hp * 64 + (((c2 * 4 + q) ^ (hp & 7)) * 8)]);
            }
#pragma unroll
            for (int g4 = 0; g4 < 4; ++g4)
#pragma unroll
                for (int p = 0; p < 4; ++p)
                    acc2[g4][p] = __builtin_amdgcn_mfma_f32_16x16x32_f16(
                        av[g4], bv[p], acc2[g4][p], 0, 0, 0);
        }
    }

    // ---- epilogue: + residual (yin), pack, transpose-store ----
    __syncthreads();                        // h1 reads done before pack overwrite
    const int colx = tx0 + m;
#pragma unroll
    for (int g4 = 0; g4 < 4; ++g4) {
#pragma unroll
        for (int p = 0; p < 4; ++p) {
            const int prow = w * 4 + p;
            const int gy   = ty0 + prow;
            const size_t pixg = pixb + (size_t)gy * 256 + colx;
            const int oc0 = g4 * 16 + q * 4;
            ushort4 a4 = *reinterpret_cast<const ushort4*>(yin + pixg * 64 + oc0);
            ushort4 pk;
#pragma unroll
            for (int r = 0; r < 4; ++r) {
                float v = acc2[g4][p][r] +
                          h2f(reinterpret_cast<const unsigned short*>(&a4)[r]);
                reinterpret_cast<unsigned short*>(&pk)[r] = f2h(v);
            }
            int pix   = prow * 16 + m;
            int part8 = g4 * 4 + q;
            int p16   = (part8 >> 1) ^ (pix & 7);
            *reinterpret_cast<ushort4*>(&smem[pix * 64 + p16 * 8 + (part8 & 1) * 4]) = pk;
        }
    }
    __syncthreads();
    for (int u = tid; u < 2048; u += 256) {
        int pix = u >> 3, p16 = u & 7;
        uint4 val = *reinterpret_cast<const uint4*>(
            &smem[pix * 64 + ((p16 ^ (pix & 7)) * 8)]);
        int gy = ty0 + (pix >> 4), gx = tx0 + (pix & 15);
        *reinterpret_cast<uint4*>(
            &yout[(pixb + (size_t)gy * 256 + gx) * 64 + p16 * 8]) = val;
    }
}

// ---------------- local similarity (LDS-tiled, fp16 dot2, di-grouped) ----------------
// Round-2 version verbatim (70 us verified).
__global__ __launch_bounds__(256)
void local_sim(
    const unsigned short* __restrict__ qh, const unsigned short* __restrict__ kh,
    unsigned short* __restrict__ att)
{
    __shared__ unsigned short lds_k[576 * 64];   // 24*24 px x 64ch fp16 = 73.7 KB

    const int tid = threadIdx.x;
    const int tx = tid & 15, ty = tid >> 4;
    const int bx = blockIdx.x * 16, by = blockIdx.y * 16;
    const int b  = blockIdx.z;
    const size_t pixb = (size_t)b * PLANE;
    const bool interior = (blockIdx.x >= 1) && (blockIdx.x <= 14) &&
                          (blockIdx.y >= 1) && (blockIdx.y <= 14);

    if (interior) {
        const unsigned short* kb =
            kh + (pixb + (size_t)(by - 4) * 256 + (bx - 4)) * 64;
#pragma unroll
        for (int it = 0; it < 18; ++it) {
            int u = it * 256 + tid;
            int pix = u >> 3, sl = u & 7;
            int part = sl ^ ((pix ^ (pix >> 3)) & 7);
            int hy = pix / 24, hx = pix - hy * 24;
            gl16(kb + ((size_t)hy * 256 + hx) * 64 + part * 8,
                 &lds_k[(it * 256 + (tid & 192)) * 8]);
        }
    } else {
        for (int u = tid; u < 4608; u += 256) {
            int pix = u >> 3, part = u & 7;
            int hy = pix / 24, hx = pix - hy * 24;
            int gy = by + hy - 4, gx = bx + hx - 4;
            uint4 val = make_uint4(0u, 0u, 0u, 0u);
            if ((unsigned)gy < 256u && (unsigned)gx < 256u)
                val = *reinterpret_cast<const uint4*>(
                    kh + ((pixb + (size_t)gy * 256 + gx) * 64 + part * 8));
            int sl = part ^ ((pix ^ (pix >> 3)) & 7);
            *reinterpret_cast<uint4*>(&lds_k[pix * 64 + sl * 8]) = val;
        }
    }
    __syncthreads();

    const unsigned short* qbase = qh + (pixb + (size_t)(by + ty) * 256 + bx + tx) * 64;
    unsigned short* op = att + (pixb + (size_t)(by + ty) * 256 + bx + tx) * 96;

    uint4 qv[8];
#pragma unroll
    for (int j = 0; j < 8; ++j)
        qv[j] = *reinterpret_cast<const uint4*>(qbase + j * 8);

#pragma unroll
    for (int g = 0; g < 3; ++g) {
        float acc[27];
#pragma unroll
        for (int i = 0; i < 27; ++i) acc[i] = 0.f;

#pragma unroll
        for (int dil = 0; dil < 3; ++dil) {
            const int hrow = (ty + g * 3 + dil) * 24 + tx;
#pragma unroll
            for (int dj = 0; dj < 9; ++dj) {
                const int hp = hrow + dj;
                const int gs = (hp ^ (hp >> 3)) & 7;
                float s = acc[dil * 9 + dj];
#pragma unroll
                for (int part = 0; part < 8; ++part) {
                    const uint4 kv = *reinterpret_cast<const uint4*>(
                        &lds_k[hp * 64 + ((part ^ gs) * 8)]);
                    s = dot2h(qv[part].x, kv.x, s);
                    s = dot2h(qv[part].y, kv.y, s);
                    s = dot2h(qv[part].z, kv.z, s);
                    s = dot2h(qv[part].w, kv.w, s);
                }
                acc[dil * 9 + dj] = s;
            }
        }

        unsigned short* o = op + g * 27;
        if (g == 0) {
            uint4 A = {pack2h(acc[0], acc[1]),  pack2h(acc[2], acc[3]),
                       pack2h(acc[4], acc[5]),  pack2h(acc[6], acc[7])};
            uint4 B = {pack2h(acc[8], acc[9]),  pack2h(acc[10], acc[11]),
                       pack2h(acc[12], acc[13]), pack2h(acc[14], acc[15])};
            uint2 C = {pack2h(acc[16], acc[17]), pack2h(acc[18], acc[19])};
            uint2 D = {pack2h(acc[20], acc[21]), pack2h(acc[22], acc[23])};
            *reinterpret_cast<uint4*>(o)      = A;
            *reinterpret_cast<uint4*>(o + 8)  = B;
            *reinterpret_cast<uint2*>(o + 16) = C;
            *reinterpret_cast<uint2*>(o + 20) = D;
            *reinterpret_cast<unsigned*>(o + 24) = pack2h(acc[24], acc[25]);
            o[26] = f2h(acc[26]);
        } else if (g == 1) {
            o[0] = f2h(acc[0]);
            *reinterpret_cast<unsigned*>(o + 1) = pack2h(acc[1], acc[2]);
            *reinterpret_cast<unsigned*>(o + 3) = pack2h(acc[3], acc[4]);
            uint4 A = {pack2h(acc[5], acc[6]),   pack2h(acc[7], acc[8]),
                       pack2h(acc[9], acc[10]),  pack2h(acc[11], acc[12])};
            uint4 B = {pack2h(acc[13], acc[14]), pack2h(acc[15], acc[16]),
                       pack2h(acc[17], acc[18]), pack2h(acc[19], acc[20])};
            *reinterpret_cast<uint4*>(o + 5)  = A;
            *reinterpret_cast<uint4*>(o + 13) = B;
            uint2 C = {pack2h(acc[21], acc[22]), pack2h(acc[23], acc[24])};
            *reinterpret_cast<uint2*>(o + 21) = C;
            *reinterpret_cast<unsigned*>(o + 25) = pack2h(acc[25], acc[26]);
        } else {
            *reinterpret_cast<unsigned*>(o) = pack2h(acc[0], acc[1]);
            uint4 A = {pack2h(acc[2], acc[3]),   pack2h(acc[4], acc[5]),
                       pack2h(acc[6], acc[7]),   pack2h(acc[8], acc[9])};
            uint4 B = {pack2h(acc[10], acc[11]), pack2h(acc[12], acc[13]),
                       pack2h(acc[14], acc[15]), pack2h(acc[16], acc[17])};
            *reinterpret_cast<uint4*>(o + 2)  = A;
            *reinterpret_cast<uint4*>(o + 10) = B;
            uint2 C = {pack2h(acc[18], acc[19]), pack2h(acc[20], acc[21])};
            *reinterpret_cast<uint2*>(o + 18) = C;
            *reinterpret_cast<unsigned*>(o + 22) = pack2h(acc[22], acc[23]);
            *reinterpret_cast<unsigned*>(o + 24) = pack2h(acc[24], acc[25]);
            o[26] = f2h(acc[26]);
        }
    }

    op[81] = 0;
    *reinterpret_cast<unsigned*>(op + 82) = 0u;
    uint2 z2 = {0u, 0u};
    uint4 z4 = {0u, 0u, 0u, 0u};
    *reinterpret_cast<uint2*>(op + 84) = z2;
    *reinterpret_cast<uint4*>(op + 88) = z4;
}

// ---------------- pack x: fp32 NCHW old/new -> fp16 [b][pix][64] ----------------
__global__ __launch_bounds__(256) void pack_x(
    const float* __restrict__ old_, const float* __restrict__ new_,
    unsigned short* __restrict__ xb)
{
    __shared__ unsigned short lds[256 * 64];
    const int tid = threadIdx.x;
    const int b = blockIdx.y;
    const size_t pixbase = (size_t)blockIdx.x * 256;
#pragma unroll
    for (int cg = 0; cg < 8; ++cg) {
        unsigned pk[4];
#pragma unroll
        for (int h = 0; h < 4; ++h) {
            int c0 = cg * 8 + h * 2;
            const float* s0 = (c0 < 32) ? old_ : new_;
            const float* s1 = ((c0 + 1) < 32) ? old_ : new_;
            float f0 = s0[((size_t)b * 32 + (c0 & 31)) * PLANE + pixbase + tid];
            float f1 = s1[((size_t)b * 32 + ((c0 + 1) & 31)) * PLANE + pixbase + tid];
            pk[h] = pack2h(f0, f1);
        }
        int p16 = cg ^ (tid & 7);
        uint4 v; v.x = pk[0]; v.y = pk[1]; v.z = pk[2]; v.w = pk[3];
        *reinterpret_cast<uint4*>(&lds[tid * 64 + p16 * 8]) = v;
    }
    __syncthreads();
    for (int r = 0; r < 8; ++r) {
        int u = r * 256 + tid;
        int pix = u >> 3, p16 = u & 7;
        uint4 v = *reinterpret_cast<const uint4*>(&lds[pix * 64 + ((p16 ^ (pix & 7)) * 8)]);
        *reinterpret_cast<uint4*>(
            &xb[((size_t)b * PLANE + pixbase + pix) * 64 + p16 * 8]) = v;
    }
}

// ---------------- weight prep: fp32 OIHW -> fp16 [9][64][CIN] ----------------
__global__ void prep_wstd(const float* __restrict__ wq, const float* __restrict__ wk,
                          const float* __restrict__ wo1, const float* __restrict__ wo2,
                          const float* __restrict__ rw1, const float* __restrict__ rw2,
                          unsigned short* __restrict__ wstd)
{
    const int c = blockIdx.y;  // 0..19
    const float* src;
    if (c == 0) src = wq;
    else if (c == 1) src = wk;
    else if (c == 2) src = wo1;
    else if (c == 3) src = wo2;
    else if (c < 12) src = rw1 + (size_t)(c - 4) * 36864;
    else src = rw2 + (size_t)(c - 12) * 36864;
    int idx = blockIdx.x * 256 + threadIdx.x;  // 0..4095
    int o = idx >> 6, i = idx & 63;
    const float* s = src + (size_t)(o * 64 + i) * 9;
    unsigned short* d = wstd + (size_t)c * 36864 + (size_t)o * 64 + i;
#pragma unroll
    for (int t = 0; t < 9; ++t) d[(size_t)t * 4096] = f2h(s[t]);
}

__global__ void prep_wv(const float* __restrict__ wv, unsigned short* __restrict__ wv96)
{
    int idx = blockIdx.x * 256 + threadIdx.x;  // < 6144
    int o = idx / 96, i = idx - o * 96;
    unsigned short* d = wv96 + (size_t)o * 96 + i;
    if (i < 81) {
        const float* s = wv + (size_t)(o * 81 + i) * 9;
#pragma unroll
        for (int t = 0; t < 9; ++t) d[(size_t)t * 6144] = f2h(s[t]);
    } else {
#pragma unroll
        for (int t = 0; t < 9; ++t) d[(size_t)t * 6144] = 0;
    }
}

extern "C" void kernel_launch(void* const* d_in, const int* in_sizes, int n_in,
                              void* d_out, int out_size, void* d_ws, size_t ws_size,
                              hipStream_t stream)
{
    const float* old_ = (const float*)d_in[0];
    const float* new_ = (const float*)d_in[1];
    const float* wq  = (const float*)d_in[2];  const float* bq  = (const float*)d_in[3];
    const float* wk  = (const float*)d_in[4];  const float* bk  = (const float*)d_in[5];
    const float* wv  = (const float*)d_in[6];  const float* bv  = (const float*)d_in[7];
    const float* wo1 = (const float*)d_in[8];  const float* bo1 = (const float*)d_in[9];
    const float* rw1 = (const float*)d_in[10]; const float* rw2 = (const float*)d_in[11];
    const float* wo2 = (const float*)d_in[12]; const float* bo2 = (const float*)d_in[13];
    float* out = (float*)d_out;

    char* ws = (char*)d_ws;
    // X : xh fp16 (32 MiB, persistent)
    // P1: q -> y_a (32 MiB) ; P2: k -> xv (32 MiB) ; P3: att96(48) -> y_b
    unsigned short* X   = (unsigned short*)(ws);
    unsigned short* P1  = (unsigned short*)(ws + 33554432ull);
    unsigned short* P2  = (unsigned short*)(ws + 67108864ull);
    unsigned short* P3  = (unsigned short*)(ws + 100663296ull);
    unsigned short* wst = (unsigned short*)(ws + 150994944ull);   // 20*36864 fp16
    unsigned short* wv96= (unsigned short*)(ws + 152469504ull);   // 9*64*96 fp16

    const dim3 cgrid(16, 16, 4), cblk(256);

    prep_wstd<<<dim3(16, 20), 256, 0, stream>>>(wq, wk, wo1, wo2, rw1, rw2, wst);
    prep_wv<<<dim3(24), 256, 0, stream>>>(wv, wv96);
    pack_x<<<dim3(256, 4), 256, 0, stream>>>(old_, new_, X);

    // q = conv(x, wq, bq); k = conv(x, wk, bk)
    conv_mfma<64, true, false, false, false, false, false, true>
        <<<cgrid, cblk, 0, stream>>>(X, wst + 0ull * 36864, bq, nullptr, nullptr, nullptr, P1);
    conv_mfma<64, true, false, false, false, false, false, true>
        <<<cgrid, cblk, 0, stream>>>(X, wst + 1ull * 36864, bk, nullptr, nullptr, nullptr, P2);
    // att (fp16, 96ch padded)
    local_sim<<<cgrid, cblk, 0, stream>>>(P1, P2, P3);
    // xv = x * (conv(att, wv) + bv)   [MULX fused]
    conv_mfma<96, true, false, false, false, true, false, true>
        <<<cgrid, cblk, 0, stream>>>(P3, wv96, bv, nullptr, X, nullptr, P2);
    // y0 = conv(xv, wo1, bo1) -> P1
    conv_mfma<64, true, false, false, false, false, false, true>
        <<<cgrid, cblk, 0, stream>>>(P2, wst + 2ull * 36864, bo1, nullptr, nullptr, nullptr, P1);
    // 8 fused ResBlocks; y ping-pong P1 <-> P3
    for (int i = 0; i < 8; ++i) {
        unsigned short* ysrc = (i & 1) ? P3 : P1;
        unsigned short* ydst = (i & 1) ? P1 : P3;
        res_fused<<<cgrid, cblk, 0, stream>>>(
            ysrc, wst + (size_t)(4 + i) * 36864, wst + (size_t)(12 + i) * 36864, ydst);
    }
    // out = conv(y, wo2, bo2) + x   [ADDX fused]; final y in P1
    conv_mfma<64, true, false, false, true, false, true, false>
        <<<cgrid, cblk, 0, stream>>>(P1, wst + 3ull * 36864, bo2, nullptr, X, out, nullptr);
}